// Round 3
// baseline (152.417 us; speedup 1.0000x reference)
//
#include <hip/hip_runtime.h>

// SNDE: 100-step Euler of  u += (tanh(u@W1+b1)@W2 + b2 - gamma*th*pinv*(1-th^2)*wg) * dt
// 4096 samples; 512 blocks x 8 waves (512 thr) x 8 samples; bf16 MFMA 16x16x32 (M=8 used).
// 2 independent blocks per CU -> decorrelated barriers hide LDS/MFMA latency.
// Wave w owns GEMM1 N-slice [32w,32w+32) == GEMM2 K-slice (same-wave h RAW, no barrier).

#define GAMMA 0.1f
#define EPSG  1e-12f

typedef __attribute__((ext_vector_type(8))) short bf16x8;
typedef __attribute__((ext_vector_type(4))) float f32x4;

__device__ __forceinline__ float ftanh(float x) {
    float e = __expf(2.0f * x);
    return 1.0f - 2.0f * __builtin_amdgcn_rcpf(e + 1.0f);
}

__device__ __forceinline__ unsigned int f2bf(float f) {
    unsigned int u = __float_as_uint(f);
    return (u + 0x7fffu + ((u >> 16) & 1u)) >> 16;
}

__global__ __launch_bounds__(512, 4) void snde_kernel(
    const float* __restrict__ y0, const float* __restrict__ t,
    const float* __restrict__ W1, const float* __restrict__ b1,
    const float* __restrict__ W2, const float* __restrict__ b2,
    const float* __restrict__ wg, const float* __restrict__ bgp,
    float* __restrict__ out)
{
    __shared__ unsigned short uAs[16 * 64];      // bf16 u A-tile (rows 8-15 zero), swizzled, 2 KB
    __shared__ unsigned short hAs[16 * 256];     // bf16 h A-tile, swizzled, 8 KB
    __shared__ float          fpart[8][16][68];  // per-wave f partials, 34.8 KB (rows 8-15 junk)

    const int tid = threadIdx.x;
    const int w   = tid >> 6;   // wave 0..7
    const int l   = tid & 63;
    const int l15 = l & 15;
    const int lg  = l >> 4;
    const int s0g = blockIdx.x * 8;

    // ---------------- weight fragments -> registers (one-time) ----------------
    // GEMM1: h(8x256) = u(8x64) @ W1(64x256). Wave w owns n in [32w, 32w+32).
    bf16x8 B1[2][2];
    #pragma unroll
    for (int nt = 0; nt < 2; ++nt) {
        const int n = w * 32 + nt * 16 + l15;
        #pragma unroll
        for (int kt = 0; kt < 2; ++kt) {
            bf16x8 v;
            #pragma unroll
            for (int j = 0; j < 8; ++j) {
                const int k = kt * 32 + lg * 8 + j;
                v[j] = (short)f2bf(W1[k * 256 + n]);
            }
            B1[nt][kt] = v;
        }
    }
    // GEMM2: f(8x64) = h(8x256) @ W2(256x64). Wave w sums k in [32w, 32w+32) (one K=32 MFMA).
    bf16x8 B2[4];
    #pragma unroll
    for (int nt = 0; nt < 4; ++nt) {
        const int n = nt * 16 + l15;
        bf16x8 v;
        #pragma unroll
        for (int j = 0; j < 8; ++j) {
            const int k = w * 32 + lg * 8 + j;
            v[j] = (short)f2bf(W2[k * 64 + n]);
        }
        B2[nt] = v;
    }

    float b1v[2];
    #pragma unroll
    for (int nt = 0; nt < 2; ++nt) b1v[nt] = b1[w * 32 + nt * 16 + l15];

    // update-phase mapping: wave w updates sample sU=w, lane handles dim dd
    const int sU = w;              // 0..7
    const int dd = l;              // 0..63
    const float wgv  = wg[dd];
    const float b2v  = b2[dd];
    float wsum = wgv * wgv;
    #pragma unroll
    for (int m = 1; m < 64; m <<= 1) wsum += __shfl_xor(wsum, m, 64);
    const float bg  = bgp[0];
    const float dtv = t[1] - t[0];

    // ---------------- init: zero uAs (incl. dead rows), load u, emit out[0] ----------------
    ((unsigned int*)uAs)[tid] = 0u;   // 512 u32 = whole uAs
    __syncthreads();
    float uv = y0[(size_t)(s0g + sU) * 64 + dd];
    {
        unsigned int boff = ((unsigned)(sU * 128 + dd * 2)) ^ ((unsigned)(sU & 7) << 4);
        *(unsigned short*)((char*)uAs + boff) = (unsigned short)f2bf(uv);
        out[(size_t)(s0g + sU) * 64 + dd] = uv;
    }
    __syncthreads();

    for (int step = 0; step < 100; ++step) {
        // ---- GEMM1: acc1 = u @ W1 + b1 (wave's 32-col N-slice) ----
        bf16x8 A1[2];
        #pragma unroll
        for (int kt = 0; kt < 2; ++kt) {
            unsigned int boff = ((unsigned)(l15 * 128 + (kt * 32 + lg * 8) * 2))
                              ^ ((unsigned)(l15 & 7) << 4);
            A1[kt] = *(const bf16x8*)((const char*)uAs + boff);
        }
        f32x4 acc1[2];
        #pragma unroll
        for (int nt = 0; nt < 2; ++nt) {
            acc1[nt][0] = b1v[nt]; acc1[nt][1] = b1v[nt];
            acc1[nt][2] = b1v[nt]; acc1[nt][3] = b1v[nt];
        }
        #pragma unroll
        for (int nt = 0; nt < 2; ++nt)
            #pragma unroll
            for (int kt = 0; kt < 2; ++kt)
                acc1[nt] = __builtin_amdgcn_mfma_f32_16x16x32_bf16(A1[kt], B1[nt][kt], acc1[nt], 0, 0, 0);

        // ---- tanh, scatter own 32-col stripe of h (rows 8-15 are finite junk) ----
        #pragma unroll
        for (int nt = 0; nt < 2; ++nt) {
            const int n = w * 32 + nt * 16 + l15;
            #pragma unroll
            for (int i = 0; i < 4; ++i) {
                const int m = lg * 4 + i;
                const float th = ftanh(acc1[nt][i]);
                unsigned int boff = ((unsigned)(m * 512 + n * 2)) ^ ((unsigned)(m & 7) << 4);
                *(unsigned short*)((char*)hAs + boff) = (unsigned short)f2bf(th);
            }
        }

        // ---- GEMM2 partial over wave's K-slice [32w, 32w+32) (same-wave RAW) ----
        bf16x8 A2;
        {
            unsigned int boff = ((unsigned)(l15 * 512 + (w * 32 + lg * 8) * 2))
                              ^ ((unsigned)(l15 & 7) << 4);
            A2 = *(const bf16x8*)((const char*)hAs + boff);
        }
        f32x4 acc2[4];
        #pragma unroll
        for (int nt = 0; nt < 4; ++nt) {
            acc2[nt][0] = 0.f; acc2[nt][1] = 0.f; acc2[nt][2] = 0.f; acc2[nt][3] = 0.f;
        }
        #pragma unroll
        for (int nt = 0; nt < 4; ++nt)
            acc2[nt] = __builtin_amdgcn_mfma_f32_16x16x32_bf16(A2, B2[nt], acc2[nt], 0, 0, 0);

        #pragma unroll
        for (int nt = 0; nt < 4; ++nt) {
            const int n = nt * 16 + l15;
            #pragma unroll
            for (int i = 0; i < 4; ++i)
                fpart[w][lg * 4 + i][n] = acc2[nt][i];
        }
        __syncthreads();

        // ---- update: f = sum of 8 partials + b2; stabilization; Euler; republish u ----
        {
            float fs = 0.f;
            #pragma unroll
            for (int p = 0; p < 8; ++p) fs += fpart[p][sU][dd];
            float zp = uv * wgv;
            #pragma unroll
            for (int m = 1; m < 64; m <<= 1) zp += __shfl_xor(zp, m, 64);
            const float th = ftanh(zp + bg);
            const float q  = 1.0f - th * th;
            const float sg = q * q * wsum;                 // = sum(G*G)
            const float pinv = (fabsf(sg) > EPSG) ? __builtin_amdgcn_rcpf(sg) : 0.0f;
            const float coef = GAMMA * th * pinv * q;      // stable_d = coef * wg_d
            const float un = uv + (fs + b2v - coef * wgv) * dtv;
            uv = un;
            unsigned int boff = ((unsigned)(sU * 128 + dd * 2)) ^ ((unsigned)(sU & 7) << 4);
            *(unsigned short*)((char*)uAs + boff) = (unsigned short)f2bf(un);
            out[(size_t)(step + 1) * (4096 * 64) + (size_t)(s0g + sU) * 64 + dd] = un;
        }
        __syncthreads();
    }
}

extern "C" void kernel_launch(void* const* d_in, const int* in_sizes, int n_in,
                              void* d_out, int out_size, void* d_ws, size_t ws_size,
                              hipStream_t stream) {
    const float* y0 = (const float*)d_in[0];
    const float* t  = (const float*)d_in[1];
    const float* W1 = (const float*)d_in[2];
    const float* b1 = (const float*)d_in[3];
    const float* W2 = (const float*)d_in[4];
    const float* b2 = (const float*)d_in[5];
    const float* wg = (const float*)d_in[6];
    const float* bg = (const float*)d_in[7];
    float* out = (float*)d_out;

    snde_kernel<<<dim3(512), dim3(512), 0, stream>>>(y0, t, W1, b1, W2, b2, wg, bg, out);
}

// Round 4
// 107.516 us; speedup vs baseline: 1.4176x; 1.4176x over previous
//
#include <hip/hip_runtime.h>

// SNDE: 100-step Euler of  u += (tanh(u@W1+b1)@W2 + b2 - gamma*th*pinv*(1-th^2)*wg) * dt
// 4096 samples; 256 blocks x 8 waves (512 thr) x 16 samples; bf16 MFMA 16x16x32.
// R3: (1) raw lgkm-only barriers (no vmcnt drain -> out stores float across steps),
//     (2) stabilization coef computed at loop top from register u, off the
//         post-barrier critical path. Numerics identical to R1.

#define GAMMA 0.1f
#define EPSG  1e-12f

typedef __attribute__((ext_vector_type(8))) short bf16x8;
typedef __attribute__((ext_vector_type(4))) float f32x4;

__device__ __forceinline__ float ftanh(float x) {
    float e = __expf(2.0f * x);
    return 1.0f - 2.0f * __builtin_amdgcn_rcpf(e + 1.0f);
}

__device__ __forceinline__ unsigned int f2bf(float f) {
    unsigned int u = __float_as_uint(f);
    return (u + 0x7fffu + ((u >> 16) & 1u)) >> 16;
}

// LDS-only barrier: order LDS ops across waves without draining vmcnt (global
// stores keep floating). Single asm block so no memory op can be scheduled
// between the wait and the barrier.
#define BARRIER_LGKM() asm volatile("s_waitcnt lgkmcnt(0)\ns_barrier" ::: "memory")

__global__ __launch_bounds__(512, 1) void snde_kernel(
    const float* __restrict__ y0, const float* __restrict__ t,
    const float* __restrict__ W1, const float* __restrict__ b1,
    const float* __restrict__ W2, const float* __restrict__ b2,
    const float* __restrict__ wg, const float* __restrict__ bgp,
    float* __restrict__ out)
{
    __shared__ unsigned short uAs[16 * 64];      // bf16 u A-tile, rows XOR-swizzled (2 KB)
    __shared__ unsigned short hAs[16 * 256];     // bf16 h A-tile, rows XOR-swizzled (8 KB)
    __shared__ float          fpart[8][16][68];  // per-wave f partials (34 KB)

    const int tid = threadIdx.x;
    const int w   = tid >> 6;   // wave 0..7
    const int l   = tid & 63;
    const int l15 = l & 15;
    const int lg  = l >> 4;
    const int s0g = blockIdx.x * 16;

    // ---------------- weight fragments -> registers (one-time) ----------------
    // GEMM1: h(16x256) = u(16x64) @ W1(64x256). Wave w owns n in [32w, 32w+32).
    bf16x8 B1[2][2];
    #pragma unroll
    for (int nt = 0; nt < 2; ++nt) {
        const int n = w * 32 + nt * 16 + l15;
        #pragma unroll
        for (int kt = 0; kt < 2; ++kt) {
            bf16x8 v;
            #pragma unroll
            for (int j = 0; j < 8; ++j) {
                const int k = kt * 32 + lg * 8 + j;
                v[j] = (short)f2bf(W1[k * 256 + n]);
            }
            B1[nt][kt] = v;
        }
    }
    // GEMM2: f(16x64) = h(16x256) @ W2(256x64). Wave w sums k in [32w, 32w+32).
    bf16x8 B2[4];
    #pragma unroll
    for (int nt = 0; nt < 4; ++nt) {
        const int n = nt * 16 + l15;
        bf16x8 v;
        #pragma unroll
        for (int j = 0; j < 8; ++j) {
            const int k = w * 32 + lg * 8 + j;
            v[j] = (short)f2bf(W2[k * 64 + n]);
        }
        B2[nt] = v;
    }

    float b1v[2];
    #pragma unroll
    for (int nt = 0; nt < 2; ++nt) b1v[nt] = b1[w * 32 + nt * 16 + l15];

    // update-phase constants: lane updates sample sU, dims dd..dd+1 (float2)
    const int sU = tid >> 5;          // 0..15
    const int dd = (tid & 31) * 2;    // 0..62
    const float2 wg2  = *(const float2*)(&wg[dd]);
    const float2 b2v2 = *(const float2*)(&b2[dd]);
    float wsum = wg2.x * wg2.x + wg2.y * wg2.y;
    #pragma unroll
    for (int m = 1; m < 32; m <<= 1) wsum += __shfl_xor(wsum, m, 64);
    const float bg  = bgp[0];
    const float dtv = t[1] - t[0];

    // ---------------- init u from y0 (registers + bf16 LDS); emit out[0] ----------------
    float2 uv;
    {
        uv = *(const float2*)(&y0[(size_t)(s0g + sU) * 64 + dd]);
        unsigned int p0 = f2bf(uv.x) | (f2bf(uv.y) << 16);
        unsigned int off = (((unsigned)(sU * 128 + dd * 2)) ^ ((unsigned)(sU & 7) << 4)) >> 2;
        ((unsigned int*)uAs)[off] = p0;
        *(float2*)(&out[(size_t)(s0g + sU) * 64 + dd]) = uv;
    }
    __syncthreads();

    for (int step = 0; step < 100; ++step) {
        // ---- stabilization coef from current u (registers) — overlaps GEMM1/2 ----
        float coef;
        {
            float zp = uv.x * wg2.x + uv.y * wg2.y;
            #pragma unroll
            for (int m = 1; m < 32; m <<= 1) zp += __shfl_xor(zp, m, 64);
            const float th = ftanh(zp + bg);
            const float q  = 1.0f - th * th;
            const float sg = q * q * wsum;                 // = sum(G*G)
            const float pinv = (fabsf(sg) > EPSG) ? __builtin_amdgcn_rcpf(sg) : 0.0f;
            coef = GAMMA * th * pinv * q;                  // stable_d = coef * wg_d
        }

        // ---- GEMM1: acc1 = u @ W1 + b1 (wave's 32-col N-slice) ----
        bf16x8 A1[2];
        #pragma unroll
        for (int kt = 0; kt < 2; ++kt) {
            unsigned int boff = ((unsigned)(l15 * 128 + (kt * 32 + lg * 8) * 2))
                              ^ ((unsigned)(l15 & 7) << 4);
            A1[kt] = *(const bf16x8*)((const char*)uAs + boff);
        }
        f32x4 acc1[2];
        #pragma unroll
        for (int nt = 0; nt < 2; ++nt) {
            acc1[nt][0] = b1v[nt]; acc1[nt][1] = b1v[nt];
            acc1[nt][2] = b1v[nt]; acc1[nt][3] = b1v[nt];
        }
        #pragma unroll
        for (int nt = 0; nt < 2; ++nt)
            #pragma unroll
            for (int kt = 0; kt < 2; ++kt)
                acc1[nt] = __builtin_amdgcn_mfma_f32_16x16x32_bf16(A1[kt], B1[nt][kt], acc1[nt], 0, 0, 0);

        // ---- tanh, scatter own 32-col stripe of h (bf16, swizzled) ----
        #pragma unroll
        for (int nt = 0; nt < 2; ++nt) {
            const int n = w * 32 + nt * 16 + l15;
            #pragma unroll
            for (int i = 0; i < 4; ++i) {
                const int m = lg * 4 + i;
                const float th = ftanh(acc1[nt][i]);
                unsigned int boff = ((unsigned)(m * 512 + n * 2)) ^ ((unsigned)(m & 7) << 4);
                *(unsigned short*)((char*)hAs + boff) = (unsigned short)f2bf(th);
            }
        }
        // same-wave RAW on hAs: wave reads back exactly the columns it wrote

        // ---- GEMM2 partial over wave's K-slice [32w, 32w+32) ----
        bf16x8 A2;
        {
            unsigned int boff = ((unsigned)(l15 * 512 + (w * 32 + lg * 8) * 2))
                              ^ ((unsigned)(l15 & 7) << 4);
            A2 = *(const bf16x8*)((const char*)hAs + boff);
        }
        f32x4 acc2[4];
        #pragma unroll
        for (int nt = 0; nt < 4; ++nt) {
            acc2[nt][0] = 0.f; acc2[nt][1] = 0.f; acc2[nt][2] = 0.f; acc2[nt][3] = 0.f;
        }
        #pragma unroll
        for (int nt = 0; nt < 4; ++nt)
            acc2[nt] = __builtin_amdgcn_mfma_f32_16x16x32_bf16(A2, B2[nt], acc2[nt], 0, 0, 0);

        #pragma unroll
        for (int nt = 0; nt < 4; ++nt) {
            const int n = nt * 16 + l15;
            #pragma unroll
            for (int i = 0; i < 4; ++i)
                fpart[w][lg * 4 + i][n] = acc2[nt][i];
        }
        BARRIER_LGKM();   // fpart visible; no vmcnt drain

        // ---- update: f = sum of 8 partials + b2; Euler with precomputed coef ----
        {
            float2 fs = {0.f, 0.f};
            #pragma unroll
            for (int p = 0; p < 8; ++p) {
                const float2 fp = *(const float2*)(&fpart[p][sU][dd]);
                fs.x += fp.x; fs.y += fp.y;
            }
            float2 un;
            un.x = uv.x + (fs.x + b2v2.x - coef * wg2.x) * dtv;
            un.y = uv.y + (fs.y + b2v2.y - coef * wg2.y) * dtv;
            uv = un;
            unsigned int p0 = f2bf(un.x) | (f2bf(un.y) << 16);
            unsigned int off = (((unsigned)(sU * 128 + dd * 2)) ^ ((unsigned)(sU & 7) << 4)) >> 2;
            ((unsigned int*)uAs)[off] = p0;
            *(float2*)(&out[(size_t)(step + 1) * (4096 * 64) + (size_t)(s0g + sU) * 64 + dd]) = un;
        }
        BARRIER_LGKM();   // uAs republish visible; out store keeps floating
    }
}

extern "C" void kernel_launch(void* const* d_in, const int* in_sizes, int n_in,
                              void* d_out, int out_size, void* d_ws, size_t ws_size,
                              hipStream_t stream) {
    const float* y0 = (const float*)d_in[0];
    const float* t  = (const float*)d_in[1];
    const float* W1 = (const float*)d_in[2];
    const float* b1 = (const float*)d_in[3];
    const float* W2 = (const float*)d_in[4];
    const float* b2 = (const float*)d_in[5];
    const float* wg = (const float*)d_in[6];
    const float* bg = (const float*)d_in[7];
    float* out = (float*)d_out;

    snde_kernel<<<dim3(256), dim3(512), 0, stream>>>(y0, t, W1, b1, W2, b2, wg, bg, out);
}